// Round 1
// baseline (192.874 us; speedup 1.0000x reference)
//
#include <hip/hip_runtime.h>

#define BB 512
#define DD 128
#define HD 64

// ---- workspace layout (float offsets) ----
#define OFF_E1 0                     // 3 * 512 * 128  (normalized emb1, packed (d, d+64))
#define OFF_E2 (3*BB*DD)             // 3 * 512 * 128
#define OFF_C1 (2*3*BB*DD)           // 2 * 512 * 128  (cert1 layers 1,2 packed)
#define OFF_C2 (OFF_C1 + 2*BB*DD)    // 2 * 512 * 128
#define OFF_AB (OFF_C2 + 2*BB*DD)    // 2 layers * (A[128], B[128]) where A=-log2e*alpha, B=-log2e*beta
#define OFF_LNK (OFF_AB + 512)       // 2 links * (idx[3][128] int, w[3][128] float) = 2*768
#define WS_FLOATS (OFF_LNK + 1536)   // 657408 floats ~ 2.51 MB

__device__ __forceinline__ float wave_sum64(float v) {
  #pragma unroll
  for (int off = 1; off < 64; off <<= 1) v += __shfl_xor(v, off, 64);
  return v;
}

// ---- prep 1: row-normalize embeddings, pack rows as float2 (v[d], v[d+64]) ----
struct PackArgs { const float* src[10]; };

__global__ __launch_bounds__(256) void pack_kernel(PackArgs a, float* __restrict__ ws) {
  const int tid  = threadIdx.x;
  const int lane = tid & 63;
  const int gw   = blockIdx.x * 4 + (tid >> 6);   // 5120 row-tasks
  const int arr  = gw >> 9;                       // 0..9
  const int row  = gw & 511;
  const float* s = a.src[arr];
  float lo = s[row * DD + lane];
  float hi = s[row * DD + lane + 64];
  float scale = 1.0f;
  if (arr < 6) {  // embeddings: L2 normalize (torch F.normalize semantics)
    float ss = wave_sum64(lo * lo + hi * hi);
    scale = 1.0f / fmaxf(sqrtf(ss), 1e-12f);
  }
  float* dst;
  if (arr < 3)      dst = ws + OFF_E1 + arr * (BB * DD);
  else if (arr < 6) dst = ws + OFF_E2 + (arr - 3) * (BB * DD);
  else if (arr < 8) dst = ws + OFF_C1 + (arr - 6) * (BB * DD);
  else              dst = ws + OFF_C2 + (arr - 8) * (BB * DD);
  ((float2*)dst)[row * HD + lane] = make_float2(lo * scale, hi * scale);
}

// ---- prep 2: per-column top-3 of each link (mask+normalize), fold alpha/beta ----
__global__ __launch_bounds__(256) void prep_kernel(const float* __restrict__ lnk0,
                                                   const float* __restrict__ lnk1,
                                                   const float* __restrict__ a1,
                                                   const float* __restrict__ b1,
                                                   const float* __restrict__ a2,
                                                   const float* __restrict__ b2,
                                                   float* __restrict__ ws) {
  const int t = threadIdx.x;      // 256 threads: 2 links x 128 columns
  const int l = t >> 7, e = t & 127;
  const float* L = l ? lnk1 : lnk0;
  float v0 = -1.f, v1 = -1.f, v2 = -1.f;
  int   p0 = 0,    p1 = 0,    p2 = 0;
  for (int d = 0; d < DD; ++d) {
    float v = L[d * DD + e];                 // coalesced across threads (e varies)
    if (v > v0)      { v2 = v1; p2 = p1; v1 = v0; p1 = p0; v0 = v; p0 = d; }
    else if (v > v1) { v2 = v1; p2 = p1; v1 = v;  p1 = d; }
    else if (v > v2) { v2 = v;  p2 = d; }
  }
  float inv = 1.0f / (v0 + v1 + v2 + 1e-8f); // column sum of masked W + EPS
  int*   li = (int*)(ws + OFF_LNK + l * 768);
  float* lw =        ws + OFF_LNK + l * 768 + 384;
  li[e] = p0; li[128 + e] = p1; li[256 + e] = p2;
  lw[e] = v0 * inv; lw[128 + e] = v1 * inv; lw[256 + e] = v2 * inv;
  // sigmoid fold: t = exp(-(alpha*eta+beta)) = exp2(A*eta + B), A=-log2e*alpha, B=-log2e*beta
  const float NL2E = -1.4426950408889634f;
  const float* al = l ? a2 : a1;
  const float* bl = l ? b2 : b1;
  ws[OFF_AB + l * 256 + e]       = NL2E * al[e];
  ws[OFF_AB + l * 256 + 128 + e] = NL2E * bl[e];
}

// ---- main: one wave per (i,j) pair; lane owns dims d=lane and d=lane+64.
// Wave-private LDS h-buffer; same-wave DS ops are in-order -> NO barriers.
__global__ __launch_bounds__(256) void main_kernel(const float* __restrict__ ws,
                                                   float* __restrict__ out) {
  __shared__ float hbuf[4][DD];
  const int tid  = threadIdx.x;
  const int lane = tid & 63;
  const int w    = tid >> 6;
  float* hb = hbuf[w];
  const int gw = blockIdx.x * 4 + w;     // 4096 waves
  const int i0 = (gw >> 5) * 4;          // 128 i-tiles of 4
  const int j0 = (gw & 31) * 16;         // 32 j-chunks of 16

  // gather indices/weights for output dims e=lane, e=lane+64 (fixed for whole kernel)
  const int*   li0 = (const int*)(ws + OFF_LNK);
  const float* lw0 = ws + OFF_LNK + 384;
  const int*   li1 = (const int*)(ws + OFF_LNK + 768);
  const float* lw1 = ws + OFF_LNK + 768 + 384;
  int I1[3][2], I2[3][2]; float W1[3][2], W2[3][2];
  #pragma unroll
  for (int k = 0; k < 3; ++k) {
    I1[k][0] = li0[k * 128 + lane]; I1[k][1] = li0[k * 128 + lane + 64];
    W1[k][0] = lw0[k * 128 + lane]; W1[k][1] = lw0[k * 128 + lane + 64];
    I2[k][0] = li1[k * 128 + lane]; I2[k][1] = li1[k * 128 + lane + 64];
    W2[k][0] = lw1[k * 128 + lane]; W2[k][1] = lw1[k * 128 + lane + 64];
  }
  const float A1lo = ws[OFF_AB + lane],       A1hi = ws[OFF_AB + lane + 64];
  const float B1lo = ws[OFF_AB + 128 + lane], B1hi = ws[OFF_AB + 128 + lane + 64];
  const float A2lo = ws[OFF_AB + 256 + lane], A2hi = ws[OFF_AB + 256 + lane + 64];
  const float B2lo = ws[OFF_AB + 384 + lane], B2hi = ws[OFF_AB + 384 + lane + 64];

  const float2* E1p = (const float2*)(ws + OFF_E1);
  const float2* E2p = (const float2*)(ws + OFF_E2);
  const float2* C1p = (const float2*)(ws + OFF_C1);
  const float2* C2p = (const float2*)(ws + OFF_C2);

  // i-tile held in registers across the j loop
  float2 e10[4], e11[4], e12[4], c11[4], c12[4];
  #pragma unroll
  for (int ii = 0; ii < 4; ++ii) {
    int i = i0 + ii;
    e10[ii] = E1p[(0 * BB + i) * HD + lane];
    e11[ii] = E1p[(1 * BB + i) * HD + lane];
    e12[ii] = E1p[(2 * BB + i) * HD + lane];
    c11[ii] = C1p[(0 * BB + i) * HD + lane];
    c12[ii] = C1p[(1 * BB + i) * HD + lane];
  }

  #pragma unroll 1
  for (int jj = 0; jj < 16; ++jj) {
    const int j = j0 + jj;
    const float2 f20 = E2p[(0 * BB + j) * HD + lane];
    const float2 f21 = E2p[(1 * BB + j) * HD + lane];
    const float2 f22 = E2p[(2 * BB + j) * HD + lane];
    const float2 g21 = C2p[(0 * BB + j) * HD + lane];
    const float2 g22 = C2p[(1 * BB + j) * HD + lane];
    #pragma unroll
    for (int ii = 0; ii < 4; ++ii) {
      // layer 0: nodes_hat = |e1-e2|^2
      float dx = e10[ii].x - f20.x, dy = e10[ii].y - f20.y;
      hb[lane] = dx * dx; hb[lane + 64] = dy * dy;
      // layer 1: sparse column-gather (top-3), sigmoid blend
      float glo = hb[I1[0][0]] * W1[0][0] + hb[I1[1][0]] * W1[1][0] + hb[I1[2][0]] * W1[2][0];
      float ghi = hb[I1[0][1]] * W1[0][1] + hb[I1[1][1]] * W1[1][1] + hb[I1[2][1]] * W1[2][1];
      dx = e11[ii].x - f21.x; dy = e11[ii].y - f21.y;
      float nlo = dx * dx, nhi = dy * dy;
      float tlo = __builtin_amdgcn_exp2f(fmaf(c11[ii].x * g21.x, A1lo, B1lo));
      float thi = __builtin_amdgcn_exp2f(fmaf(c11[ii].y * g21.y, A1hi, B1hi));
      float Plo = __builtin_amdgcn_rcpf(1.0f + tlo);   // P = sigmoid(alpha*eta+beta)
      float Phi = __builtin_amdgcn_rcpf(1.0f + thi);
      float hlo = fmaf(Plo, nlo - glo, glo);           // (1-P)*g + P*n
      float hhi = fmaf(Phi, nhi - ghi, ghi);
      hb[lane] = hlo; hb[lane + 64] = hhi;
      // layer 2
      glo = hb[I2[0][0]] * W2[0][0] + hb[I2[1][0]] * W2[1][0] + hb[I2[2][0]] * W2[2][0];
      ghi = hb[I2[0][1]] * W2[0][1] + hb[I2[1][1]] * W2[1][1] + hb[I2[2][1]] * W2[2][1];
      dx = e12[ii].x - f22.x; dy = e12[ii].y - f22.y;
      nlo = dx * dx; nhi = dy * dy;
      tlo = __builtin_amdgcn_exp2f(fmaf(c12[ii].x * g22.x, A2lo, B2lo));
      thi = __builtin_amdgcn_exp2f(fmaf(c12[ii].y * g22.y, A2hi, B2hi));
      Plo = __builtin_amdgcn_rcpf(1.0f + tlo);
      Phi = __builtin_amdgcn_rcpf(1.0f + thi);
      hlo = fmaf(Plo, nlo - glo, glo);
      hhi = fmaf(Phi, nhi - ghi, ghi);
      // final: ovr_sim = sum_d nodes_hat
      float s = wave_sum64(hlo + hhi);
      if (lane == 0) out[(i0 + ii) * BB + j] = s;
    }
  }
}

extern "C" void kernel_launch(void* const* d_in, const int* in_sizes, int n_in,
                              void* d_out, int out_size, void* d_ws, size_t ws_size,
                              hipStream_t stream) {
  (void)in_sizes; (void)n_in; (void)out_size; (void)ws_size;
  // setup_inputs dict order:
  // [0]emb1_0 [1]emb2_0 [2]cert1_0 [3]cert2_0 [4]alpha_0 [5]beta_0
  // [6]emb1_1 [7]emb2_1 [8]cert1_1 [9]cert2_1 [10]alpha_1 [11]beta_1
  // [12]emb1_2 [13]emb2_2 [14]cert1_2 [15]cert2_2 [16]alpha_2 [17]beta_2
  // [18]link_0 [19]link_1
  float* ws = (float*)d_ws;
  PackArgs pa;
  pa.src[0] = (const float*)d_in[0];  pa.src[1] = (const float*)d_in[6];  pa.src[2] = (const float*)d_in[12];
  pa.src[3] = (const float*)d_in[1];  pa.src[4] = (const float*)d_in[7];  pa.src[5] = (const float*)d_in[13];
  pa.src[6] = (const float*)d_in[8];  pa.src[7] = (const float*)d_in[14];
  pa.src[8] = (const float*)d_in[9];  pa.src[9] = (const float*)d_in[15];
  hipLaunchKernelGGL(pack_kernel, dim3(1280), dim3(256), 0, stream, pa, ws);
  hipLaunchKernelGGL(prep_kernel, dim3(1), dim3(256), 0, stream,
                     (const float*)d_in[18], (const float*)d_in[19],
                     (const float*)d_in[10], (const float*)d_in[11],
                     (const float*)d_in[16], (const float*)d_in[17], ws);
  hipLaunchKernelGGL(main_kernel, dim3(1024), dim3(256), 0, stream,
                     (const float*)ws, (float*)d_out);
}

// Round 3
// 168.985 us; speedup vs baseline: 1.1414x; 1.1414x over previous
//
#include <hip/hip_runtime.h>

#define BB 512
#define DD 128
#define HD 64

// ---- workspace layout (float offsets) ----
#define OFF_E1 0                     // 3 * 512 * 128  (normalized emb1, packed (d, d+64))
#define OFF_E2 (3*BB*DD)             // 3 * 512 * 128
#define OFF_C1 (2*3*BB*DD)           // 2 * 512 * 128  (cert1 layers 1,2 packed)
#define OFF_C2 (OFF_C1 + 2*BB*DD)    // 2 * 512 * 128
#define OFF_AB (OFF_C2 + 2*BB*DD)    // 2 layers * (A[128], B[128]); A=-log2e*alpha, B=-log2e*beta
#define OFF_LNK (OFF_AB + 512)       // 2 links * (idx[3][128] int, w[3][128] float) = 2*768
#define WS_FLOATS (OFF_LNK + 1536)   // ~2.51 MB

__device__ __forceinline__ float wave_sum64(float v) {
  #pragma unroll
  for (int off = 1; off < 64; off <<= 1) v += __shfl_xor(v, off, 64);
  return v;
}

// DPP lane-shift add: pure VALU pipe (no LDS). Sum of all 64 lanes lands in lane 63.
template <int CTRL>
__device__ __forceinline__ float dpp_mov(float x) {
  int i = __builtin_bit_cast(int, x);
  int r = __builtin_amdgcn_update_dpp(0, i, CTRL, 0xF, 0xF, false);
  return __builtin_bit_cast(float, r);
}
__device__ __forceinline__ float dpp_wave_sum_lane63(float v) {
  v += dpp_mov<0x111>(v);  // row_shr:1
  v += dpp_mov<0x112>(v);  // row_shr:2
  v += dpp_mov<0x114>(v);  // row_shr:4
  v += dpp_mov<0x118>(v);  // row_shr:8  -> lane15 of each row16 has row sum
  v += dpp_mov<0x142>(v);  // row_bcast:15 -> lane31 = S(0:31), lane63 = S(32:63)
  v += dpp_mov<0x143>(v);  // row_bcast:31 -> lane63 = S(0:63)
  return v;
}

// ---- merged prep: blocks 0..1279 normalize/pack rows; block 1280 does link top-3 ----
struct PackArgs { const float* src[10]; };

__global__ __launch_bounds__(256) void prep_kernel(PackArgs a,
                                                   const float* __restrict__ lnk0,
                                                   const float* __restrict__ lnk1,
                                                   const float* __restrict__ a1,
                                                   const float* __restrict__ b1,
                                                   const float* __restrict__ a2,
                                                   const float* __restrict__ b2,
                                                   float* __restrict__ ws) {
  const int tid = threadIdx.x;
  if (blockIdx.x < 1280) {
    const int lane = tid & 63;
    const int gw   = blockIdx.x * 4 + (tid >> 6);
    const int arr  = gw >> 9;                       // 0..9
    const int row  = gw & 511;
    const float* s = a.src[arr];
    float lo = s[row * DD + lane];
    float hi = s[row * DD + lane + 64];
    float scale = 1.0f;
    if (arr < 6) {  // embeddings: L2 normalize
      float ss = wave_sum64(lo * lo + hi * hi);
      scale = 1.0f / fmaxf(sqrtf(ss), 1e-12f);
    }
    float* dst;
    if (arr < 3)      dst = ws + OFF_E1 + arr * (BB * DD);
    else if (arr < 6) dst = ws + OFF_E2 + (arr - 3) * (BB * DD);
    else if (arr < 8) dst = ws + OFF_C1 + (arr - 6) * (BB * DD);
    else              dst = ws + OFF_C2 + (arr - 8) * (BB * DD);
    ((float2*)dst)[row * HD + lane] = make_float2(lo * scale, hi * scale);
  } else {
    // link prep: 256 threads = 2 links x 128 columns
    const int l = tid >> 7, e = tid & 127;
    const float* L = l ? lnk1 : lnk0;
    float v0 = -1.f, v1 = -1.f, v2 = -1.f;
    int   p0 = 0,    p1 = 0,    p2 = 0;
    for (int d = 0; d < DD; ++d) {
      float v = L[d * DD + e];
      if (v > v0)      { v2 = v1; p2 = p1; v1 = v0; p1 = p0; v0 = v; p0 = d; }
      else if (v > v1) { v2 = v1; p2 = p1; v1 = v;  p1 = d; }
      else if (v > v2) { v2 = v;  p2 = d; }
    }
    float inv = 1.0f / (v0 + v1 + v2 + 1e-8f);
    int*   li = (int*)(ws + OFF_LNK + l * 768);
    float* lw =        ws + OFF_LNK + l * 768 + 384;
    // store indices pre-transformed for the interleaved LDS h-layout:
    // dim d lives at LDS word ((d&63)<<1) | (d>>6)
    li[e]       = ((p0 & 63) << 1) | (p0 >> 6);
    li[128 + e] = ((p1 & 63) << 1) | (p1 >> 6);
    li[256 + e] = ((p2 & 63) << 1) | (p2 >> 6);
    lw[e] = v0 * inv; lw[128 + e] = v1 * inv; lw[256 + e] = v2 * inv;
    const float NL2E = -1.4426950408889634f;
    const float* al = l ? a2 : a1;
    const float* bl = l ? b2 : b1;
    ws[OFF_AB + l * 256 + e]       = NL2E * al[e];
    ws[OFF_AB + l * 256 + 128 + e] = NL2E * bl[e];
  }
}

// ---- main: one wave per (i-tile of 4) x (j-chunk of 16); lane owns dims (lane, lane+64).
// Layer-1 gather factored exactly (per-dim):
//   g0[e] = Sum_k w1_k[e]*(u0[d_k]-v0[d_k])^2
//         = SU[e] + SV[e] + Sum_k (-2*w1_k[e]*u0[d_k]) * v0[d_k]
// with SU = Sum_k w1_k*u0[d_k]^2 (per-ii), SV = Sum_k w1_k*v0[d_k]^2 (per-jj).
// Only the layer-2 gather stays per-pair in LDS (interleaved layout, ds_write_b64 spill).
// Reduction via DPP (VALU pipe, no LDS).
__global__ __launch_bounds__(256, 4) void main_kernel(const float* __restrict__ ws,
                                                      float* __restrict__ out) {
  __shared__ float hbuf[4][DD];
  const int tid  = threadIdx.x;
  const int lane = tid & 63;
  const int w    = tid >> 6;
  float* hb = hbuf[w];
  float2* hb2 = (float2*)hb;             // hb2[l] = (dim l, dim l+64)
  const int gw = blockIdx.x * 4 + w;     // 4096 waves
  const int i0 = (gw >> 5) * 4;          // 128 i-tiles of 4
  const int j0 = (gw & 31) * 16;         // 32 j-chunks of 16

  const int*   li0 = (const int*)(ws + OFF_LNK);
  const float* lw0 = ws + OFF_LNK + 384;
  const int*   li1 = (const int*)(ws + OFF_LNK + 768);
  const float* lw1 = ws + OFF_LNK + 768 + 384;
  int I1[3][2], I2[3][2]; float W1[3][2], W2[3][2];
  #pragma unroll
  for (int k = 0; k < 3; ++k) {
    I1[k][0] = li0[k * 128 + lane]; I1[k][1] = li0[k * 128 + lane + 64];
    W1[k][0] = lw0[k * 128 + lane]; W1[k][1] = lw0[k * 128 + lane + 64];
    I2[k][0] = li1[k * 128 + lane]; I2[k][1] = li1[k * 128 + lane + 64];
    W2[k][0] = lw1[k * 128 + lane]; W2[k][1] = lw1[k * 128 + lane + 64];
  }
  const float A1lo = ws[OFF_AB + lane],       A1hi = ws[OFF_AB + lane + 64];
  const float B1lo = ws[OFF_AB + 128 + lane], B1hi = ws[OFF_AB + 128 + lane + 64];
  const float A2lo = ws[OFF_AB + 256 + lane], A2hi = ws[OFF_AB + 256 + lane + 64];
  const float B2lo = ws[OFF_AB + 384 + lane], B2hi = ws[OFF_AB + 384 + lane + 64];

  const float2* E1p = (const float2*)(ws + OFF_E1);
  const float2* E2p = (const float2*)(ws + OFF_E2);
  const float2* C1p = (const float2*)(ws + OFF_C1);
  const float2* C2p = (const float2*)(ws + OFF_C2);

  // i-tile setup: gather u0 at layer-1 indices once per ii (amortized over 16 j's)
  float U[4][3][2];       // -2*w1_k*u0[d_k]
  float SU[4][2];         // Sum_k w1_k*u0[d_k]^2
  float2 u1[4], u2[4], c11[4], c12[4];
  #pragma unroll
  for (int ii = 0; ii < 4; ++ii) {
    const int i = i0 + ii;
    float2 u0 = E1p[(0 * BB + i) * HD + lane];
    hb2[lane] = u0;                               // same-wave DS: in-order, no barrier
    SU[ii][0] = 0.0f; SU[ii][1] = 0.0f;
    #pragma unroll
    for (int k = 0; k < 3; ++k) {
      float alo = hb[I1[k][0]], ahi = hb[I1[k][1]];
      float tlo = W1[k][0] * alo, thi = W1[k][1] * ahi;
      SU[ii][0] = fmaf(tlo, alo, SU[ii][0]);
      SU[ii][1] = fmaf(thi, ahi, SU[ii][1]);
      U[ii][k][0] = -2.0f * tlo;
      U[ii][k][1] = -2.0f * thi;
    }
    u1[ii]  = E1p[(1 * BB + i) * HD + lane];
    u2[ii]  = E1p[(2 * BB + i) * HD + lane];
    c11[ii] = C1p[(0 * BB + i) * HD + lane];
    c12[ii] = C1p[(1 * BB + i) * HD + lane];
  }

  #pragma unroll 1
  for (int jj = 0; jj < 16; ++jj) {
    const int j = j0 + jj;
    float2 v0 = E2p[(0 * BB + j) * HD + lane];
    hb2[lane] = v0;
    float V[3][2], SVlo = 0.0f, SVhi = 0.0f;
    #pragma unroll
    for (int k = 0; k < 3; ++k) {
      float clo = hb[I1[k][0]], chi = hb[I1[k][1]];
      V[k][0] = clo; V[k][1] = chi;
      SVlo = fmaf(W1[k][0] * clo, clo, SVlo);
      SVhi = fmaf(W1[k][1] * chi, chi, SVhi);
    }
    const float2 v1  = E2p[(1 * BB + j) * HD + lane];
    const float2 v2  = E2p[(2 * BB + j) * HD + lane];
    const float2 g21 = C2p[(0 * BB + j) * HD + lane];
    const float2 g22 = C2p[(1 * BB + j) * HD + lane];
    #pragma unroll
    for (int ii = 0; ii < 4; ++ii) {
      // layer 1: g0 from factored gathers (registers only)
      float glo = fmaf(U[ii][0][0], V[0][0],
                  fmaf(U[ii][1][0], V[1][0],
                  fmaf(U[ii][2][0], V[2][0], SU[ii][0] + SVlo)));
      float ghi = fmaf(U[ii][0][1], V[0][1],
                  fmaf(U[ii][1][1], V[1][1],
                  fmaf(U[ii][2][1], V[2][1], SU[ii][1] + SVhi)));
      float dx = u1[ii].x - v1.x, dy = u1[ii].y - v1.y;
      float nlo = dx * dx, nhi = dy * dy;
      float tlo = __builtin_amdgcn_exp2f(fmaf(c11[ii].x * g21.x, A1lo, B1lo));
      float thi = __builtin_amdgcn_exp2f(fmaf(c11[ii].y * g21.y, A1hi, B1hi));
      float Plo = __builtin_amdgcn_rcpf(1.0f + tlo);   // P = sigmoid(alpha*eta+beta)
      float Phi = __builtin_amdgcn_rcpf(1.0f + thi);
      float hlo = fmaf(Plo, nlo - glo, glo);           // (1-P)*g + P*n
      float hhi = fmaf(Phi, nhi - ghi, ghi);
      // layer 2: per-pair LDS gather (P is pair-dependent); one b64 spill
      hb2[lane] = make_float2(hlo, hhi);
      glo = hb[I2[0][0]] * W2[0][0] + hb[I2[1][0]] * W2[1][0] + hb[I2[2][0]] * W2[2][0];
      ghi = hb[I2[0][1]] * W2[0][1] + hb[I2[1][1]] * W2[1][1] + hb[I2[2][1]] * W2[2][1];
      dx = u2[ii].x - v2.x; dy = u2[ii].y - v2.y;
      nlo = dx * dx; nhi = dy * dy;
      tlo = __builtin_amdgcn_exp2f(fmaf(c12[ii].x * g22.x, A2lo, B2lo));
      thi = __builtin_amdgcn_exp2f(fmaf(c12[ii].y * g22.y, A2hi, B2hi));
      Plo = __builtin_amdgcn_rcpf(1.0f + tlo);
      Phi = __builtin_amdgcn_rcpf(1.0f + thi);
      hlo = fmaf(Plo, nlo - glo, glo);
      hhi = fmaf(Phi, nhi - ghi, ghi);
      // reduce over 128 dims: DPP (VALU pipe), sum lands in lane 63
      float s = dpp_wave_sum_lane63(hlo + hhi);
      if (lane == 63) out[(i0 + ii) * BB + j] = s;
    }
  }
}

extern "C" void kernel_launch(void* const* d_in, const int* in_sizes, int n_in,
                              void* d_out, int out_size, void* d_ws, size_t ws_size,
                              hipStream_t stream) {
  (void)in_sizes; (void)n_in; (void)out_size; (void)ws_size;
  // dict order: [0]emb1_0 [1]emb2_0 [2]cert1_0 [3]cert2_0 [4]alpha_0 [5]beta_0
  //             [6..11] layer1, [12..17] layer2, [18]link_0 [19]link_1
  float* ws = (float*)d_ws;
  PackArgs pa;
  pa.src[0] = (const float*)d_in[0];  pa.src[1] = (const float*)d_in[6];  pa.src[2] = (const float*)d_in[12];
  pa.src[3] = (const float*)d_in[1];  pa.src[4] = (const float*)d_in[7];  pa.src[5] = (const float*)d_in[13];
  pa.src[6] = (const float*)d_in[8];  pa.src[7] = (const float*)d_in[14];
  pa.src[8] = (const float*)d_in[9];  pa.src[9] = (const float*)d_in[15];
  hipLaunchKernelGGL(prep_kernel, dim3(1281), dim3(256), 0, stream, pa,
                     (const float*)d_in[18], (const float*)d_in[19],
                     (const float*)d_in[10], (const float*)d_in[11],
                     (const float*)d_in[16], (const float*)d_in[17], ws);
  hipLaunchKernelGGL(main_kernel, dim3(1024), dim3(256), 0, stream,
                     (const float*)ws, (float*)d_out);
}

// Round 4
// 135.879 us; speedup vs baseline: 1.4195x; 1.2436x over previous
//
#include <hip/hip_runtime.h>

#define BB 512
#define DD 128
#define HD 64

// ---- workspace layout (float offsets) ----
#define OFF_E1 0                     // 3 * 512 * 128  (normalized emb1, packed (d, d+64))
#define OFF_E2 (3*BB*DD)             // 3 * 512 * 128
#define OFF_C1 (2*3*BB*DD)           // 2 * 512 * 128  (cert1 layers 1,2 packed)
#define OFF_C2 (OFF_C1 + 2*BB*DD)    // 2 * 512 * 128
#define OFF_AB (OFF_C2 + 2*BB*DD)    // 2 layers * (A[128], B[128]); A=-log2e*alpha, B=-log2e*beta
#define OFF_LNK (OFF_AB + 512)       // 2 links * (idx[3][128] int, w[3][128] float) = 2*768
#define WS_FLOATS (OFF_LNK + 1536)   // ~2.51 MB

__device__ __forceinline__ float wave_sum64(float v) {
  #pragma unroll
  for (int off = 1; off < 64; off <<= 1) v += __shfl_xor(v, off, 64);
  return v;
}

// DPP lane-shift add: pure VALU pipe (no LDS). Sum of all 64 lanes lands in lane 63.
template <int CTRL>
__device__ __forceinline__ float dpp_mov(float x) {
  int i = __builtin_bit_cast(int, x);
  int r = __builtin_amdgcn_update_dpp(0, i, CTRL, 0xF, 0xF, false);
  return __builtin_bit_cast(float, r);
}
__device__ __forceinline__ float dpp_wave_sum_lane63(float v) {
  v += dpp_mov<0x111>(v);  // row_shr:1
  v += dpp_mov<0x112>(v);  // row_shr:2
  v += dpp_mov<0x114>(v);  // row_shr:4
  v += dpp_mov<0x118>(v);  // row_shr:8  -> lane15 of each row16 has row sum
  v += dpp_mov<0x142>(v);  // row_bcast:15 -> lane31 = S(0:31), lane63 = S(32:63)
  v += dpp_mov<0x143>(v);  // row_bcast:31 -> lane63 = S(0:63)
  return v;
}

// ---- merged prep ----
// blocks 0..1279: normalize/pack rows (5120 row-tasks, one wave each)
// blocks 1280..1343: link top-3, one wave per (link, column) task (256 tasks)
//   R3 post-mortem: the old single-block serial 128-iter top-3 loop was
//   latency-serialized (~900 cyc/load -> ~50 us). Wave-parallel argmax fixes it.
struct PackArgs { const float* src[10]; };

__global__ __launch_bounds__(256) void prep_kernel(PackArgs a,
                                                   const float* __restrict__ lnk0,
                                                   const float* __restrict__ lnk1,
                                                   const float* __restrict__ a1,
                                                   const float* __restrict__ b1,
                                                   const float* __restrict__ a2,
                                                   const float* __restrict__ b2,
                                                   float* __restrict__ ws) {
  const int tid  = threadIdx.x;
  const int lane = tid & 63;
  if (blockIdx.x < 1280) {
    const int gw   = blockIdx.x * 4 + (tid >> 6);
    const int arr  = gw >> 9;                       // 0..9
    const int row  = gw & 511;
    const float* s = a.src[arr];
    float lo = s[row * DD + lane];
    float hi = s[row * DD + lane + 64];
    float scale = 1.0f;
    if (arr < 6) {  // embeddings: L2 normalize
      float ss = wave_sum64(lo * lo + hi * hi);
      scale = 1.0f / fmaxf(sqrtf(ss), 1e-12f);
    }
    float* dst;
    if (arr < 3)      dst = ws + OFF_E1 + arr * (BB * DD);
    else if (arr < 6) dst = ws + OFF_E2 + (arr - 3) * (BB * DD);
    else if (arr < 8) dst = ws + OFF_C1 + (arr - 6) * (BB * DD);
    else              dst = ws + OFF_C2 + (arr - 8) * (BB * DD);
    ((float2*)dst)[row * HD + lane] = make_float2(lo * scale, hi * scale);
  } else {
    // one wave per (l, e) column; lane d holds L[d][e] and L[d+64][e]
    const int task = (blockIdx.x - 1280) * 4 + (tid >> 6);   // 0..255
    const int l = task >> 7, e = task & 127;
    const float* L = l ? lnk1 : lnk0;
    float v0 = L[lane * DD + e];
    float v1 = L[(lane + 64) * DD + e];
    float bv[3]; int bd[3];
    #pragma unroll
    for (int k = 0; k < 3; ++k) {
      float lv; int ld;
      if (v0 >= v1) { lv = v0; ld = lane; } else { lv = v1; ld = lane + 64; }
      #pragma unroll
      for (int off = 1; off < 64; off <<= 1) {
        float ov = __shfl_xor(lv, off, 64);
        int   od = __shfl_xor(ld, off, 64);
        if (ov > lv || (ov == lv && od < ld)) { lv = ov; ld = od; }
      }
      bv[k] = lv; bd[k] = ld;             // same in all lanes
      if (ld == lane)      v0 = -1e30f;   // remove winner
      if (ld == lane + 64) v1 = -1e30f;
    }
    if (lane == 0) {
      float inv = 1.0f / (bv[0] + bv[1] + bv[2] + 1e-8f);
      int*   li = (int*)(ws + OFF_LNK + l * 768);
      float* lw =        ws + OFF_LNK + l * 768 + 384;
      // store indices pre-transformed for the interleaved LDS h-layout:
      // dim d lives at LDS word ((d&63)<<1) | (d>>6)
      li[e]       = ((bd[0] & 63) << 1) | (bd[0] >> 6);
      li[128 + e] = ((bd[1] & 63) << 1) | (bd[1] >> 6);
      li[256 + e] = ((bd[2] & 63) << 1) | (bd[2] >> 6);
      lw[e] = bv[0] * inv; lw[128 + e] = bv[1] * inv; lw[256 + e] = bv[2] * inv;
      const float NL2E = -1.4426950408889634f;
      const float* al = l ? a2 : a1;
      const float* bl = l ? b2 : b1;
      ws[OFF_AB + l * 256 + e]       = NL2E * al[e];
      ws[OFF_AB + l * 256 + 128 + e] = NL2E * bl[e];
    }
  }
}

// ---- main: one wave per (i-tile of 4) x (j-chunk of 16); lane owns dims (lane, lane+64).
// Layer-1 gather factored exactly (per-dim):
//   g0[e] = Sum_k w1_k[e]*(u0[d_k]-v0[d_k])^2
//         = SU[e] + SV[e] + Sum_k (-2*w1_k[e]*u0[d_k]) * v0[d_k]
// with SU = Sum_k w1_k*u0[d_k]^2 (per-ii), SV = Sum_k w1_k*v0[d_k]^2 (per-jj).
// Only the layer-2 gather stays per-pair in LDS (interleaved layout, ds_write_b64 spill).
// Reduction via DPP (VALU pipe, no LDS).
__global__ __launch_bounds__(256, 4) void main_kernel(const float* __restrict__ ws,
                                                      float* __restrict__ out) {
  __shared__ float hbuf[4][DD];
  const int tid  = threadIdx.x;
  const int lane = tid & 63;
  const int w    = tid >> 6;
  float* hb = hbuf[w];
  float2* hb2 = (float2*)hb;             // hb2[l] = (dim l, dim l+64)
  const int gw = blockIdx.x * 4 + w;     // 4096 waves
  const int i0 = (gw >> 5) * 4;          // 128 i-tiles of 4
  const int j0 = (gw & 31) * 16;         // 32 j-chunks of 16

  const int*   li0 = (const int*)(ws + OFF_LNK);
  const float* lw0 = ws + OFF_LNK + 384;
  const int*   li1 = (const int*)(ws + OFF_LNK + 768);
  const float* lw1 = ws + OFF_LNK + 768 + 384;
  int I1[3][2], I2[3][2]; float W1[3][2], W2[3][2];
  #pragma unroll
  for (int k = 0; k < 3; ++k) {
    I1[k][0] = li0[k * 128 + lane]; I1[k][1] = li0[k * 128 + lane + 64];
    W1[k][0] = lw0[k * 128 + lane]; W1[k][1] = lw0[k * 128 + lane + 64];
    I2[k][0] = li1[k * 128 + lane]; I2[k][1] = li1[k * 128 + lane + 64];
    W2[k][0] = lw1[k * 128 + lane]; W2[k][1] = lw1[k * 128 + lane + 64];
  }
  const float A1lo = ws[OFF_AB + lane],       A1hi = ws[OFF_AB + lane + 64];
  const float B1lo = ws[OFF_AB + 128 + lane], B1hi = ws[OFF_AB + 128 + lane + 64];
  const float A2lo = ws[OFF_AB + 256 + lane], A2hi = ws[OFF_AB + 256 + lane + 64];
  const float B2lo = ws[OFF_AB + 384 + lane], B2hi = ws[OFF_AB + 384 + lane + 64];

  const float2* E1p = (const float2*)(ws + OFF_E1);
  const float2* E2p = (const float2*)(ws + OFF_E2);
  const float2* C1p = (const float2*)(ws + OFF_C1);
  const float2* C2p = (const float2*)(ws + OFF_C2);

  // i-tile setup: gather u0 at layer-1 indices once per ii (amortized over 16 j's)
  float U[4][3][2];       // -2*w1_k*u0[d_k]
  float SU[4][2];         // Sum_k w1_k*u0[d_k]^2
  float2 u1[4], u2[4], c11[4], c12[4];
  #pragma unroll
  for (int ii = 0; ii < 4; ++ii) {
    const int i = i0 + ii;
    float2 u0 = E1p[(0 * BB + i) * HD + lane];
    hb2[lane] = u0;                               // same-wave DS: in-order, no barrier
    SU[ii][0] = 0.0f; SU[ii][1] = 0.0f;
    #pragma unroll
    for (int k = 0; k < 3; ++k) {
      float alo = hb[I1[k][0]], ahi = hb[I1[k][1]];
      float tlo = W1[k][0] * alo, thi = W1[k][1] * ahi;
      SU[ii][0] = fmaf(tlo, alo, SU[ii][0]);
      SU[ii][1] = fmaf(thi, ahi, SU[ii][1]);
      U[ii][k][0] = -2.0f * tlo;
      U[ii][k][1] = -2.0f * thi;
    }
    u1[ii]  = E1p[(1 * BB + i) * HD + lane];
    u2[ii]  = E1p[(2 * BB + i) * HD + lane];
    c11[ii] = C1p[(0 * BB + i) * HD + lane];
    c12[ii] = C1p[(1 * BB + i) * HD + lane];
  }

  #pragma unroll 1
  for (int jj = 0; jj < 16; ++jj) {
    const int j = j0 + jj;
    float2 v0 = E2p[(0 * BB + j) * HD + lane];
    hb2[lane] = v0;
    float V[3][2], SVlo = 0.0f, SVhi = 0.0f;
    #pragma unroll
    for (int k = 0; k < 3; ++k) {
      float clo = hb[I1[k][0]], chi = hb[I1[k][1]];
      V[k][0] = clo; V[k][1] = chi;
      SVlo = fmaf(W1[k][0] * clo, clo, SVlo);
      SVhi = fmaf(W1[k][1] * chi, chi, SVhi);
    }
    const float2 v1  = E2p[(1 * BB + j) * HD + lane];
    const float2 v2  = E2p[(2 * BB + j) * HD + lane];
    const float2 g21 = C2p[(0 * BB + j) * HD + lane];
    const float2 g22 = C2p[(1 * BB + j) * HD + lane];
    #pragma unroll
    for (int ii = 0; ii < 4; ++ii) {
      // layer 1: g0 from factored gathers (registers only)
      float glo = fmaf(U[ii][0][0], V[0][0],
                  fmaf(U[ii][1][0], V[1][0],
                  fmaf(U[ii][2][0], V[2][0], SU[ii][0] + SVlo)));
      float ghi = fmaf(U[ii][0][1], V[0][1],
                  fmaf(U[ii][1][1], V[1][1],
                  fmaf(U[ii][2][1], V[2][1], SU[ii][1] + SVhi)));
      float dx = u1[ii].x - v1.x, dy = u1[ii].y - v1.y;
      float nlo = dx * dx, nhi = dy * dy;
      float tlo = __builtin_amdgcn_exp2f(fmaf(c11[ii].x * g21.x, A1lo, B1lo));
      float thi = __builtin_amdgcn_exp2f(fmaf(c11[ii].y * g21.y, A1hi, B1hi));
      float Plo = __builtin_amdgcn_rcpf(1.0f + tlo);   // P = sigmoid(alpha*eta+beta)
      float Phi = __builtin_amdgcn_rcpf(1.0f + thi);
      float hlo = fmaf(Plo, nlo - glo, glo);           // (1-P)*g + P*n
      float hhi = fmaf(Phi, nhi - ghi, ghi);
      // layer 2: per-pair LDS gather (P is pair-dependent); one b64 spill
      hb2[lane] = make_float2(hlo, hhi);
      glo = hb[I2[0][0]] * W2[0][0] + hb[I2[1][0]] * W2[1][0] + hb[I2[2][0]] * W2[2][0];
      ghi = hb[I2[0][1]] * W2[0][1] + hb[I2[1][1]] * W2[1][1] + hb[I2[2][1]] * W2[2][1];
      dx = u2[ii].x - v2.x; dy = u2[ii].y - v2.y;
      nlo = dx * dx; nhi = dy * dy;
      tlo = __builtin_amdgcn_exp2f(fmaf(c12[ii].x * g22.x, A2lo, B2lo));
      thi = __builtin_amdgcn_exp2f(fmaf(c12[ii].y * g22.y, A2hi, B2hi));
      Plo = __builtin_amdgcn_rcpf(1.0f + tlo);
      Phi = __builtin_amdgcn_rcpf(1.0f + thi);
      hlo = fmaf(Plo, nlo - glo, glo);
      hhi = fmaf(Phi, nhi - ghi, ghi);
      // reduce over 128 dims: DPP (VALU pipe), sum lands in lane 63
      float s = dpp_wave_sum_lane63(hlo + hhi);
      if (lane == 63) out[(i0 + ii) * BB + j] = s;
    }
  }
}

extern "C" void kernel_launch(void* const* d_in, const int* in_sizes, int n_in,
                              void* d_out, int out_size, void* d_ws, size_t ws_size,
                              hipStream_t stream) {
  (void)in_sizes; (void)n_in; (void)out_size; (void)ws_size;
  // dict order: [0]emb1_0 [1]emb2_0 [2]cert1_0 [3]cert2_0 [4]alpha_0 [5]beta_0
  //             [6..11] layer1, [12..17] layer2, [18]link_0 [19]link_1
  float* ws = (float*)d_ws;
  PackArgs pa;
  pa.src[0] = (const float*)d_in[0];  pa.src[1] = (const float*)d_in[6];  pa.src[2] = (const float*)d_in[12];
  pa.src[3] = (const float*)d_in[1];  pa.src[4] = (const float*)d_in[7];  pa.src[5] = (const float*)d_in[13];
  pa.src[6] = (const float*)d_in[8];  pa.src[7] = (const float*)d_in[14];
  pa.src[8] = (const float*)d_in[9];  pa.src[9] = (const float*)d_in[15];
  hipLaunchKernelGGL(prep_kernel, dim3(1344), dim3(256), 0, stream, pa,
                     (const float*)d_in[18], (const float*)d_in[19],
                     (const float*)d_in[10], (const float*)d_in[11],
                     (const float*)d_in[16], (const float*)d_in[17], ws);
  hipLaunchKernelGGL(main_kernel, dim3(1024), dim3(256), 0, stream,
                     (const float*)ws, (float*)d_out);
}